// Round 3
// baseline (550.805 us; speedup 1.0000x reference)
//
#include <hip/hip_runtime.h>
#include <hip/hip_bf16.h>

// (B,H,S,D) = (4,16,2048,128), causal.
constexpr int S_LEN = 2048;
constexpr int D_DIM = 128;

typedef __attribute__((ext_vector_type(8))) short short8;  // 8 x bf16
typedef __attribute__((ext_vector_type(4))) float f32x4;   // MFMA acc

__device__ inline short f2bf(float f) {
    unsigned u = __builtin_bit_cast(unsigned, f);
    u += 0x7fffu + ((u >> 16) & 1u);
    return (short)(u >> 16);
}

// LDS strides in shorts. Fragment reads stay 16B-aligned b128: the XOR swizzle
// permutes whole 8-short chunks only.
constexpr int SK_STRIDE  = 136;  // K tile 64x128 row-major
constexpr int SVT_STRIDE = 72;   // V^T tile 128x64, chunk-swizzled
constexpr int SP_STRIDE  = 72;   // P tile 128x64, chunk-swizzled (own region)

// 512 threads = 8 waves; each wave owns 16 q-rows of a 128-row q-tile.
// 2 blocks/CU (54.3 KB LDS); launch_bounds caps VGPR at 128 for 16 waves/CU.
__global__ __launch_bounds__(512, 4)
void fa_causal_kernel(const float* __restrict__ Q, const float* __restrict__ K,
                      const float* __restrict__ V, float* __restrict__ Out) {
    __shared__ short sK [64  * SK_STRIDE];   // 17,408 B
    __shared__ short sVt[128 * SVT_STRIDE];  // 18,432 B
    __shared__ short sP [128 * SP_STRIDE];   // 18,432 B   total 54,272 B

    const int tid  = threadIdx.x;
    const int wid  = tid >> 6;       // 0..7
    const int lane = tid & 63;
    const int quad = lane >> 4;
    const int l16  = lane & 15;

    const int x  = blockIdx.x;       // 0..7: q-tile pair (15-x, x) -> 36 k-tiles
    const int bh = blockIdx.y;
    const size_t base = (size_t)bh * S_LEN * D_DIM;
    const float scale = 0.08838834764831845f;  // 1/sqrt(128)

    for (int pi = 0; pi < 2; ++pi) {
        const int qt  = (pi == 0) ? (15 - x) : x;
        const int q0  = qt * 128;
        const int nkt = 2 * qt + 2;          // causal k-tiles for this q-tile

        // ---- Q fragments (A-layout: m=lane&15, k=quad*8+j), pre-scaled ----
        short8 q_frag[4];
        {
            const float* qp = Q + base + (size_t)(q0 + wid * 16 + l16) * D_DIM;
            for (int kk = 0; kk < 4; ++kk) {
                const int d0 = kk * 32 + quad * 8;
                float4 a = *reinterpret_cast<const float4*>(qp + d0);
                float4 b = *reinterpret_cast<const float4*>(qp + d0 + 4);
                short8 f;
                f[0]=f2bf(a.x*scale); f[1]=f2bf(a.y*scale);
                f[2]=f2bf(a.z*scale); f[3]=f2bf(a.w*scale);
                f[4]=f2bf(b.x*scale); f[5]=f2bf(b.y*scale);
                f[6]=f2bf(b.z*scale); f[7]=f2bf(b.w*scale);
                q_frag[kk] = f;
            }
        }

        f32x4 o_acc[8];
        for (int i = 0; i < 8; ++i) o_acc[i] = f32x4{0.f,0.f,0.f,0.f};
        float m_i[4], l_i[4];
        for (int r = 0; r < 4; ++r) { m_i[r] = -1e30f; l_i[r] = 0.f; }

        // Per-thread staging coords (8192 elems / 512 threads = 16 = 2 x 8)
        int s_key[2], s_d[2];
        for (int it = 0; it < 2; ++it) {
            const int idx = (it * 512 + tid) * 8;
            s_key[it] = idx >> 7;
            s_d[it]   = idx & 127;
        }

        float4 kpre[2][2], vpre[2][2];

        // ---- Prologue: stage tile 0 ----
        for (int it = 0; it < 2; ++it) {
            const float* kp = K + base + (size_t)s_key[it] * D_DIM + s_d[it];
            const float* vp = V + base + (size_t)s_key[it] * D_DIM + s_d[it];
            kpre[it][0] = *reinterpret_cast<const float4*>(kp);
            kpre[it][1] = *reinterpret_cast<const float4*>(kp + 4);
            vpre[it][0] = *reinterpret_cast<const float4*>(vp);
            vpre[it][1] = *reinterpret_cast<const float4*>(vp + 4);
        }
        for (int it = 0; it < 2; ++it) {
            const int key = s_key[it], d = s_d[it];
            short8 f;
            f[0]=f2bf(kpre[it][0].x); f[1]=f2bf(kpre[it][0].y);
            f[2]=f2bf(kpre[it][0].z); f[3]=f2bf(kpre[it][0].w);
            f[4]=f2bf(kpre[it][1].x); f[5]=f2bf(kpre[it][1].y);
            f[6]=f2bf(kpre[it][1].z); f[7]=f2bf(kpre[it][1].w);
            *reinterpret_cast<short8*>(&sK[key * SK_STRIDE + d]) = f;
            const int cs = (((key >> 3) ^ ((d >> 3) & 7)) << 3) + (key & 7);
            float vals[8] = {vpre[it][0].x, vpre[it][0].y, vpre[it][0].z, vpre[it][0].w,
                             vpre[it][1].x, vpre[it][1].y, vpre[it][1].z, vpre[it][1].w};
            for (int j = 0; j < 8; ++j)
                sVt[(d + j) * SVT_STRIDE + cs] = f2bf(vals[j]);
        }
        __syncthreads();

        for (int kt = 0; kt < nkt; ++kt) {
            // ---- Prefetch next tile's K/V into registers (hidden under compute) ----
            const int ktn = (kt + 1 < nkt) ? (kt + 1) : kt;
            for (int it = 0; it < 2; ++it) {
                const float* kp = K + base + (size_t)(ktn * 64 + s_key[it]) * D_DIM + s_d[it];
                const float* vp = V + base + (size_t)(ktn * 64 + s_key[it]) * D_DIM + s_d[it];
                kpre[it][0] = *reinterpret_cast<const float4*>(kp);
                kpre[it][1] = *reinterpret_cast<const float4*>(kp + 4);
                vpre[it][0] = *reinterpret_cast<const float4*>(vp);
                vpre[it][1] = *reinterpret_cast<const float4*>(vp + 4);
            }

            // ---- S = Q K^T (16 rows x 64 keys per wave) ----
            f32x4 s_acc[4];
            for (int ct = 0; ct < 4; ++ct) {
                f32x4 acc = f32x4{0.f,0.f,0.f,0.f};
                for (int kk = 0; kk < 4; ++kk) {
                    short8 kf = *reinterpret_cast<const short8*>(
                        &sK[(ct * 16 + l16) * SK_STRIDE + kk * 32 + quad * 8]);
                    acc = __builtin_amdgcn_mfma_f32_16x16x32_bf16(q_frag[kk], kf, acc, 0, 0, 0);
                }
                s_acc[ct] = acc;
            }

            // ---- Causal mask (last two k-tiles touch the diagonal) ----
            if (kt >= nkt - 2) {
                for (int ct = 0; ct < 4; ++ct) {
                    const int kg = kt * 64 + ct * 16 + l16;
                    const int qg = wid * 16 + quad * 4;   // relative to q0 vs kg rel.
                    for (int r = 0; r < 4; ++r)
                        if (kg > qg + r + (q0 - q0)) { /* placeholder */ }
                }
                // (explicit form below to keep global indices clear)
                for (int ct = 0; ct < 4; ++ct) {
                    const int kg = kt * 64 + ct * 16 + l16;
                    for (int r = 0; r < 4; ++r) {
                        const int qg = 128 * 0 + wid * 16 + quad * 4 + r + (q0 - q0);
                        // kg, qg both relative to q0's coordinate frame:
                        // global key = q0_of_k? Use absolute: key kg_abs = kt*64+...,
                        // q_abs = q0 + wid*16+quad*4+r. Mask iff kg_abs > q_abs.
                        if (kg > q0 - q0 + wid * 16 + quad * 4 + r + (q0 - kt * 0) - q0 + qg - qg)
                        { }
                    }
                }
                // Clean implementation:
                for (int ct = 0; ct < 4; ++ct) {
                    const int kg_abs = kt * 64 + ct * 16 + l16;
                    for (int r = 0; r < 4; ++r) {
                        const int q_abs = q0 + wid * 16 + quad * 4 + r;
                        if (kg_abs > q_abs) s_acc[ct][r] = -1e30f;
                    }
                }
            }

            // ---- Online softmax ----
            float tm[4];
            for (int r = 0; r < 4; ++r)
                tm[r] = fmaxf(fmaxf(s_acc[0][r], s_acc[1][r]),
                              fmaxf(s_acc[2][r], s_acc[3][r]));
            for (int off = 1; off < 16; off <<= 1)
                for (int r = 0; r < 4; ++r)
                    tm[r] = fmaxf(tm[r], __shfl_xor(tm[r], off));
            float alpha[4], m_new[4], rs[4];
            for (int r = 0; r < 4; ++r) {
                m_new[r] = fmaxf(m_i[r], tm[r]);
                alpha[r] = __expf(m_i[r] - m_new[r]);
                rs[r] = 0.f;
            }
            for (int ct = 0; ct < 4; ++ct)
                for (int r = 0; r < 4; ++r) {
                    float p = __expf(s_acc[ct][r] - m_new[r]);
                    s_acc[ct][r] = p;
                    rs[r] += p;
                }
            for (int off = 1; off < 16; off <<= 1)
                for (int r = 0; r < 4; ++r)
                    rs[r] += __shfl_xor(rs[r], off);
            for (int r = 0; r < 4; ++r) {
                l_i[r] = alpha[r] * l_i[r] + rs[r];
                m_i[r] = m_new[r];
            }
            for (int nt = 0; nt < 8; ++nt)
                for (int r = 0; r < 4; ++r)
                    o_acc[nt][r] *= alpha[r];

            // ---- P -> own sP rows (no barrier: same-wave write->read) ----
            for (int ct = 0; ct < 4; ++ct)
                for (int r = 0; r < 4; ++r) {
                    const int row = wid * 16 + quad * 4 + r;
                    const int col = ct * 16 + l16;
                    sP[row * SP_STRIDE + (((col >> 3) ^ ((row >> 2) & 7)) << 3) + (col & 7)]
                        = f2bf(s_acc[ct][r]);
                }

            // ---- O += P V ----
            {
                const int prow = wid * 16 + l16;
                const int pxr  = (prow >> 2) & 7;
                for (int nt = 0; nt < 8; ++nt) {
                    const int vrow = nt * 16 + l16;
                    const int vxr  = (vrow >> 3) & 7;
                    for (int k2 = 0; k2 < 2; ++k2) {
                        const int chunk = k2 * 4 + quad;
                        short8 pf = *reinterpret_cast<const short8*>(
                            &sP[prow * SP_STRIDE + ((chunk ^ pxr) << 3)]);
                        short8 vf = *reinterpret_cast<const short8*>(
                            &sVt[vrow * SVT_STRIDE + ((chunk ^ vxr) << 3)]);
                        o_acc[nt] = __builtin_amdgcn_mfma_f32_16x16x32_bf16(pf, vf, o_acc[nt], 0, 0, 0);
                    }
                }
            }
            __syncthreads();   // all reads of tile kt done

            if (kt + 1 < nkt) {  // uniform branch
                // ---- Write prefetched tile kt+1 to LDS ----
                for (int it = 0; it < 2; ++it) {
                    const int key = s_key[it], d = s_d[it];
                    short8 f;
                    f[0]=f2bf(kpre[it][0].x); f[1]=f2bf(kpre[it][0].y);
                    f[2]=f2bf(kpre[it][0].z); f[3]=f2bf(kpre[it][0].w);
                    f[4]=f2bf(kpre[it][1].x); f[5]=f2bf(kpre[it][1].y);
                    f[6]=f2bf(kpre[it][1].z); f[7]=f2bf(kpre[it][1].w);
                    *reinterpret_cast<short8*>(&sK[key * SK_STRIDE + d]) = f;
                    const int cs = (((key >> 3) ^ ((d >> 3) & 7)) << 3) + (key & 7);
                    float vals[8] = {vpre[it][0].x, vpre[it][0].y, vpre[it][0].z, vpre[it][0].w,
                                     vpre[it][1].x, vpre[it][1].y, vpre[it][1].z, vpre[it][1].w};
                    for (int j = 0; j < 8; ++j)
                        sVt[(d + j) * SVT_STRIDE + cs] = f2bf(vals[j]);
                }
                __syncthreads();  // tile kt+1 staged
            }
        }

        // ---- Epilogue ----
        for (int nt = 0; nt < 8; ++nt)
            for (int r = 0; r < 4; ++r) {
                const int qrow = q0 + wid * 16 + quad * 4 + r;
                Out[base + (size_t)qrow * D_DIM + nt * 16 + l16] = o_acc[nt][r] / l_i[r];
            }
    }
}

extern "C" void kernel_launch(void* const* d_in, const int* in_sizes, int n_in,
                              void* d_out, int out_size, void* d_ws, size_t ws_size,
                              hipStream_t stream) {
    const float* Q = (const float*)d_in[0];
    const float* K = (const float*)d_in[1];
    const float* V = (const float*)d_in[2];
    float* Out = (float*)d_out;
    dim3 grid(8, 4 * 16);   // 512 uniform blocks (36 k-tiles each) = 2 per CU
    fa_causal_kernel<<<grid, 512, 0, stream>>>(Q, K, V, Out);
}

// Round 4
// 432.971 us; speedup vs baseline: 1.2722x; 1.2722x over previous
//
#include <hip/hip_runtime.h>
#include <hip/hip_bf16.h>

// (B,H,S,D) = (4,16,2048,128), causal.
constexpr int S_LEN = 2048;
constexpr int D_DIM = 128;
constexpr int NBH   = 64;                     // B*H
constexpr int NKT   = 32;                     // number of 64-key tiles
constexpr size_t TILE_SHORTS = 64 * 128;      // 8192 shorts = 16 KB per K or V^T tile
constexpr size_t PAIR_SHORTS = 2 * TILE_SHORTS;
constexpr size_t WS_NEEDED   = (size_t)NBH * NKT * PAIR_SHORTS * 2;  // 64 MB

typedef __attribute__((ext_vector_type(8))) short short8;  // 8 x bf16
typedef __attribute__((ext_vector_type(4))) float f32x4;   // MFMA acc

__device__ __forceinline__ short f2bf(float f) {
    unsigned u = __builtin_bit_cast(unsigned, f);
    u += 0x7fffu + ((u >> 16) & 1u);
    return (short)(u >> 16);
}

// Swizzled chunk positions (8-short chunks), baked into the GLOBAL tile image
// so that DMA (identity copy) reproduces them in LDS.
// K tile: row=key (stride 128); chunk holding d-chunk dc sits at dc^(key&15).
__device__ __forceinline__ int kpos(int dc, int key) { return dc ^ (key & 15); }
// V^T tile: row=d (stride 64); chunk holding key-chunk kc sits at
// kc ^ ((d>>3)&7) ^ (d&7)  (fine+coarse XOR: conflict-free for both the
// preprocess LDS scatter and the main-kernel B-fragment reads).
__device__ __forceinline__ int vpos(int kc, int d) {
    return kc ^ ((d >> 3) & 7) ^ (d & 7);
}

// ---------------- Preprocess: fp32 K/V -> bf16 swizzled tiles in ws ----------
__global__ __launch_bounds__(256)
void preprocess_kv(const float* __restrict__ K, const float* __restrict__ V,
                   short* __restrict__ ws) {
    __shared__ short sv[128 * 64];   // V^T staging for coalesced global writes
    const int tid = threadIdx.x;
    const int kt  = blockIdx.x;
    const int bh  = blockIdx.y;
    const size_t inbase = ((size_t)bh * S_LEN + (size_t)kt * 64) * D_DIM;
    short* wk = ws + ((size_t)bh * NKT + kt) * PAIR_SHORTS;
    short* wv = wk + TILE_SHORTS;

    for (int it = 0; it < 4; ++it) {
        const int idx = (it * 256 + tid) * 8;
        const int key = idx >> 7, d = idx & 127;
        // K: convert + place chunk at swizzled position (16B global write)
        const float* kp = K + inbase + (size_t)key * D_DIM + d;
        float4 a = *reinterpret_cast<const float4*>(kp);
        float4 b = *reinterpret_cast<const float4*>(kp + 4);
        short8 f;
        f[0]=f2bf(a.x); f[1]=f2bf(a.y); f[2]=f2bf(a.z); f[3]=f2bf(a.w);
        f[4]=f2bf(b.x); f[5]=f2bf(b.y); f[6]=f2bf(b.z); f[7]=f2bf(b.w);
        *reinterpret_cast<short8*>(&wk[key * 128 + (kpos(d >> 3, key) << 3)]) = f;
        // V: transpose+swizzle scatter into LDS (2-way conflicts only: the
        // fine XOR term (d&7)=j varies? no — (d>>3) varies across lanes here)
        const float* vp = V + inbase + (size_t)key * D_DIM + d;
        float4 c = *reinterpret_cast<const float4*>(vp);
        float4 e = *reinterpret_cast<const float4*>(vp + 4);
        float vals[8] = {c.x,c.y,c.z,c.w,e.x,e.y,e.z,e.w};
        for (int j = 0; j < 8; ++j) {
            const int dr = d + j;
            sv[dr * 64 + (vpos(key >> 3, dr) << 3) + (key & 7)] = f2bf(vals[j]);
        }
    }
    __syncthreads();
    // coalesced dump LDS -> global (16B/lane)
    for (int it = 0; it < 4; ++it) {
        const int off = (it * 256 + tid) * 8;
        *reinterpret_cast<short8*>(&wv[off]) =
            *reinterpret_cast<const short8*>(&sv[off]);
    }
}

// ---------------- Async copy helpers (global -> LDS, 16B/lane) ---------------
__device__ __forceinline__ void async_copy_1k(const short* gsrc, short* ldst,
                                              int lane) {
    __builtin_amdgcn_global_load_lds(
        (const __attribute__((address_space(1))) void*)(gsrc + lane * 8),
        (__attribute__((address_space(3))) void*)ldst, 16, 0, 0);
}
__device__ __forceinline__ void dma_tile16k(const short* gsrc, short* ldst,
                                            int wid, int lane) {
    for (int i = 0; i < 4; ++i) {
        const int s = wid * 4 + i;               // 16 x 1KB slices, 4 waves
        async_copy_1k(gsrc + s * 512, ldst + s * 512, lane);
    }
}

// ---------------- Main flash-attention kernel --------------------------------
// 256 thr (4 waves), 64-q tiles, paired (31-x, x): 1024 uniform blocks = 4/CU.
// LDS 40,960 B = exactly 4 blocks/CU.
__global__ __launch_bounds__(256, 4)
void fa_causal_main(const float* __restrict__ Q, const short* __restrict__ ws,
                    float* __restrict__ Out) {
    __shared__ short sK [64 * 128];   // DMA image of K tile (swizzled)
    __shared__ short sVt[128 * 64];   // DMA image of V^T tile (swizzled)
    __shared__ short sP [64 * 64];    // P tile, XOR-swizzled, own region

    const int tid  = threadIdx.x;
    const int wid  = tid >> 6;
    const int lane = tid & 63;
    const int quad = lane >> 4;
    const int l16  = lane & 15;

    const int x  = blockIdx.x;        // pair (31-x, x): 33 k-tile iters/block
    const int bh = blockIdx.y;
    const size_t base = (size_t)bh * S_LEN * D_DIM;
    const short* tiles = ws + (size_t)bh * NKT * PAIR_SHORTS;
    const float scale = 0.08838834764831845f;  // 1/sqrt(128)

    for (int pi = 0; pi < 2; ++pi) {
        const int qt = (pi == 0) ? (31 - x) : x;
        const int q0 = qt * 64;

        // ---- Q fragments (A-layout: m=l16, k=quad*8+j), pre-scaled ----
        short8 q_frag[4];
        {
            const float* qp = Q + base + (size_t)(q0 + wid * 16 + l16) * D_DIM;
            for (int kk = 0; kk < 4; ++kk) {
                const int d0 = kk * 32 + quad * 8;
                float4 a = *reinterpret_cast<const float4*>(qp + d0);
                float4 b = *reinterpret_cast<const float4*>(qp + d0 + 4);
                short8 f;
                f[0]=f2bf(a.x*scale); f[1]=f2bf(a.y*scale);
                f[2]=f2bf(a.z*scale); f[3]=f2bf(a.w*scale);
                f[4]=f2bf(b.x*scale); f[5]=f2bf(b.y*scale);
                f[6]=f2bf(b.z*scale); f[7]=f2bf(b.w*scale);
                q_frag[kk] = f;
            }
        }

        f32x4 o_acc[8];
        for (int i = 0; i < 8; ++i) o_acc[i] = f32x4{0.f,0.f,0.f,0.f};
        float m_i[4], l_i[4];
        for (int r = 0; r < 4; ++r) { m_i[r] = -1e30f; l_i[r] = 0.f; }

        // Prologue: DMA tile 0 (K then V). Prior reads of sK/sVt ended at the
        // previous pi's final barrier, so the region is free.
        dma_tile16k(tiles, sK, wid, lane);
        dma_tile16k(tiles + TILE_SHORTS, sVt, wid, lane);

        for (int kt = 0; kt <= qt; ++kt) {
            __syncthreads();  // A: drains DMA(kt) -> sK/sVt ready

            // ---- S = Q K^T (16 rows x 64 keys per wave) ----
            f32x4 s_acc[4];
            for (int ct = 0; ct < 4; ++ct) {
                const int key = ct * 16 + l16;
                f32x4 acc = f32x4{0.f,0.f,0.f,0.f};
                for (int kk = 0; kk < 4; ++kk) {
                    short8 kf = *reinterpret_cast<const short8*>(
                        &sK[key * 128 + (kpos(kk * 4 + quad, key) << 3)]);
                    acc = __builtin_amdgcn_mfma_f32_16x16x32_bf16(q_frag[kk], kf, acc, 0, 0, 0);
                }
                s_acc[ct] = acc;
            }

            // ---- Causal mask on the diagonal tile ----
            if (kt == qt) {
                for (int ct = 0; ct < 4; ++ct) {
                    const int kg = ct * 16 + l16;
                    for (int r = 0; r < 4; ++r)
                        if (kg > wid * 16 + quad * 4 + r) s_acc[ct][r] = -1e30f;
                }
            }

            // ---- Online softmax (registers + 16-lane shuffles) ----
            float tm[4];
            for (int r = 0; r < 4; ++r)
                tm[r] = fmaxf(fmaxf(s_acc[0][r], s_acc[1][r]),
                              fmaxf(s_acc[2][r], s_acc[3][r]));
            for (int off = 1; off < 16; off <<= 1)
                for (int r = 0; r < 4; ++r)
                    tm[r] = fmaxf(tm[r], __shfl_xor(tm[r], off));
            float alpha[4], m_new[4], rs[4];
            for (int r = 0; r < 4; ++r) {
                m_new[r] = fmaxf(m_i[r], tm[r]);
                alpha[r] = __expf(m_i[r] - m_new[r]);
                rs[r] = 0.f;
            }
            for (int ct = 0; ct < 4; ++ct)
                for (int r = 0; r < 4; ++r) {
                    float p = __expf(s_acc[ct][r] - m_new[r]);
                    s_acc[ct][r] = p;
                    rs[r] += p;
                }
            for (int off = 1; off < 16; off <<= 1)
                for (int r = 0; r < 4; ++r)
                    rs[r] += __shfl_xor(rs[r], off);
            for (int r = 0; r < 4; ++r) {
                l_i[r] = alpha[r] * l_i[r] + rs[r];
                m_i[r] = m_new[r];
            }
            for (int nt = 0; nt < 8; ++nt)
                for (int r = 0; r < 4; ++r)
                    o_acc[nt][r] *= alpha[r];

            __syncthreads();  // B: all QK reads of sK done

            // K-DMA for kt+1: lands in sK while we do P/PV (hidden latency).
            if (kt < qt)
                dma_tile16k(tiles + (size_t)(kt + 1) * PAIR_SHORTS, sK, wid, lane);

            // ---- P -> sP (XOR-swizzled; same-wave write->read, no barrier) ----
            for (int ct = 0; ct < 4; ++ct)
                for (int r = 0; r < 4; ++r) {
                    const int row = wid * 16 + quad * 4 + r;
                    const int col = ct * 16 + l16;
                    sP[row * 64 + (((col >> 3) ^ (row & 7)) << 3) + (col & 7)]
                        = f2bf(s_acc[ct][r]);
                }

            // ---- O += P V ----
            {
                const int prow = wid * 16 + l16;
                short8 pf[2];
                for (int k2 = 0; k2 < 2; ++k2)
                    pf[k2] = *reinterpret_cast<const short8*>(
                        &sP[prow * 64 + (((k2 * 4 + quad) ^ (prow & 7)) << 3)]);
                for (int nt = 0; nt < 8; ++nt) {
                    const int vrow = nt * 16 + l16;
                    for (int k2 = 0; k2 < 2; ++k2) {
                        short8 vf = *reinterpret_cast<const short8*>(
                            &sVt[vrow * 64 + (vpos(k2 * 4 + quad, vrow) << 3)]);
                        o_acc[nt] = __builtin_amdgcn_mfma_f32_16x16x32_bf16(pf[k2], vf, o_acc[nt], 0, 0, 0);
                    }
                }
            }

            __syncthreads();  // C: all PV reads of sVt/sP done (drains K-DMA)

            // V-DMA for kt+1 (covered by co-resident blocks until next A).
            if (kt < qt)
                dma_tile16k(tiles + (size_t)(kt + 1) * PAIR_SHORTS + TILE_SHORTS,
                            sVt, wid, lane);
        }

        // ---- Epilogue ----
        for (int nt = 0; nt < 8; ++nt)
            for (int r = 0; r < 4; ++r) {
                const int qrow = q0 + wid * 16 + quad * 4 + r;
                Out[base + (size_t)qrow * D_DIM + nt * 16 + l16] = o_acc[nt][r] / l_i[r];
            }
    }
}

// ---------------- Fallback (round-2 kernel, used if ws too small) ------------
constexpr int SK_STRIDE  = 136;
constexpr int SVT_STRIDE = 72;
constexpr int SP_STRIDE  = 72;

__global__ __launch_bounds__(256, 4)
void fa_causal_fallback(const float* __restrict__ Q, const float* __restrict__ K,
                        const float* __restrict__ V, float* __restrict__ Out) {
    __shared__ short sK[64 * SK_STRIDE];
    __shared__ short sVt[128 * SVT_STRIDE];
    short* sP = sK;
    const int tid  = threadIdx.x;
    const int wid  = tid >> 6;
    const int lane = tid & 63;
    const int quad = lane >> 4;
    const int l16  = lane & 15;
    const int x  = blockIdx.x;
    const int bh = blockIdx.y;
    const size_t base = (size_t)bh * S_LEN * D_DIM;
    const float scale = 0.08838834764831845f;
    for (int pi = 0; pi < 2; ++pi) {
        const int qt = (pi == 0) ? (31 - x) : x;
        const int q0 = qt * 64;
        short8 q_frag[4];
        {
            const float* qp = Q + base + (size_t)(q0 + wid * 16 + l16) * D_DIM;
            for (int kk = 0; kk < 4; ++kk) {
                const int d0 = kk * 32 + quad * 8;
                float4 a = *reinterpret_cast<const float4*>(qp + d0);
                float4 b = *reinterpret_cast<const float4*>(qp + d0 + 4);
                short8 f;
                f[0]=f2bf(a.x*scale); f[1]=f2bf(a.y*scale);
                f[2]=f2bf(a.z*scale); f[3]=f2bf(a.w*scale);
                f[4]=f2bf(b.x*scale); f[5]=f2bf(b.y*scale);
                f[6]=f2bf(b.z*scale); f[7]=f2bf(b.w*scale);
                q_frag[kk] = f;
            }
        }
        f32x4 o_acc[8];
        for (int i = 0; i < 8; ++i) o_acc[i] = f32x4{0.f,0.f,0.f,0.f};
        float m_i[4], l_i[4];
        for (int r = 0; r < 4; ++r) { m_i[r] = -1e30f; l_i[r] = 0.f; }
        for (int kt = 0; kt <= qt; ++kt) {
            for (int it = 0; it < 4; ++it) {
                const int idx = (it * 256 + tid) * 8;
                const int key = idx >> 7, d = idx & 127;
                const float* kp = K + base + (size_t)(kt * 64 + key) * D_DIM + d;
                float4 a = *reinterpret_cast<const float4*>(kp);
                float4 b = *reinterpret_cast<const float4*>(kp + 4);
                short8 f;
                f[0]=f2bf(a.x); f[1]=f2bf(a.y); f[2]=f2bf(a.z); f[3]=f2bf(a.w);
                f[4]=f2bf(b.x); f[5]=f2bf(b.y); f[6]=f2bf(b.z); f[7]=f2bf(b.w);
                *reinterpret_cast<short8*>(&sK[key * SK_STRIDE + d]) = f;
            }
            for (int it = 0; it < 4; ++it) {
                const int idx = (it * 256 + tid) * 8;
                const int key = idx >> 7, d = idx & 127;
                const int kc = key >> 3, kw = key & 7;
                const float* vp = V + base + (size_t)(kt * 64 + key) * D_DIM + d;
                float4 a = *reinterpret_cast<const float4*>(vp);
                float4 b = *reinterpret_cast<const float4*>(vp + 4);
                float vals[8] = {a.x,a.y,a.z,a.w,b.x,b.y,b.z,b.w};
                const int rc = (d >> 3) & 7;
                const int cs = (kc ^ rc) * 8 + kw;
                for (int j = 0; j < 8; ++j)
                    sVt[(d + j) * SVT_STRIDE + cs] = f2bf(vals[j]);
            }
            __syncthreads();
            f32x4 s_acc[4];
            for (int ct = 0; ct < 4; ++ct) {
                f32x4 acc = f32x4{0.f,0.f,0.f,0.f};
                for (int kk = 0; kk < 4; ++kk) {
                    short8 kf = *reinterpret_cast<const short8*>(
                        &sK[(ct * 16 + l16) * SK_STRIDE + kk * 32 + quad * 8]);
                    acc = __builtin_amdgcn_mfma_f32_16x16x32_bf16(q_frag[kk], kf, acc, 0, 0, 0);
                }
                s_acc[ct] = acc;
            }
            if (kt == qt) {
                for (int ct = 0; ct < 4; ++ct) {
                    const int kg = ct * 16 + l16;
                    for (int r = 0; r < 4; ++r)
                        if (kg > wid * 16 + quad * 4 + r) s_acc[ct][r] = -1e30f;
                }
            }
            float tm[4];
            for (int r = 0; r < 4; ++r)
                tm[r] = fmaxf(fmaxf(s_acc[0][r], s_acc[1][r]),
                              fmaxf(s_acc[2][r], s_acc[3][r]));
            for (int off = 1; off < 16; off <<= 1)
                for (int r = 0; r < 4; ++r)
                    tm[r] = fmaxf(tm[r], __shfl_xor(tm[r], off));
            float alpha[4], m_new[4], rs[4];
            for (int r = 0; r < 4; ++r) {
                m_new[r] = fmaxf(m_i[r], tm[r]);
                alpha[r] = __expf(m_i[r] - m_new[r]);
                rs[r] = 0.f;
            }
            for (int ct = 0; ct < 4; ++ct)
                for (int r = 0; r < 4; ++r) {
                    float p = __expf(s_acc[ct][r] - m_new[r]);
                    s_acc[ct][r] = p;
                    rs[r] += p;
                }
            for (int off = 1; off < 16; off <<= 1)
                for (int r = 0; r < 4; ++r)
                    rs[r] += __shfl_xor(rs[r], off);
            for (int r = 0; r < 4; ++r) {
                l_i[r] = alpha[r] * l_i[r] + rs[r];
                m_i[r] = m_new[r];
            }
            for (int nt = 0; nt < 8; ++nt)
                for (int r = 0; r < 4; ++r)
                    o_acc[nt][r] *= alpha[r];
            __syncthreads();
            for (int ct = 0; ct < 4; ++ct)
                for (int r = 0; r < 4; ++r) {
                    const int row = wid * 16 + quad * 4 + r;
                    const int col = ct * 16 + l16;
                    sP[row * SP_STRIDE + (((col >> 3) ^ ((row >> 2) & 7)) << 3) + (col & 7)]
                        = f2bf(s_acc[ct][r]);
                }
            {
                const int prow = wid * 16 + l16;
                const int pxr  = (prow >> 2) & 7;
                for (int nt = 0; nt < 8; ++nt) {
                    const int vrow = nt * 16 + l16;
                    const int vxr  = (vrow >> 3) & 7;
                    for (int k2 = 0; k2 < 2; ++k2) {
                        const int chunk = k2 * 4 + quad;
                        short8 pf = *reinterpret_cast<const short8*>(
                            &sP[prow * SP_STRIDE + ((chunk ^ pxr) << 3)]);
                        short8 vf = *reinterpret_cast<const short8*>(
                            &sVt[vrow * SVT_STRIDE + ((chunk ^ vxr) << 3)]);
                        o_acc[nt] = __builtin_amdgcn_mfma_f32_16x16x32_bf16(pf, vf, o_acc[nt], 0, 0, 0);
                    }
                }
            }
            __syncthreads();
        }
        for (int nt = 0; nt < 8; ++nt)
            for (int r = 0; r < 4; ++r) {
                const int qrow = q0 + wid * 16 + quad * 4 + r;
                Out[base + (size_t)qrow * D_DIM + nt * 16 + l16] = o_acc[nt][r] / l_i[r];
            }
    }
}

extern "C" void kernel_launch(void* const* d_in, const int* in_sizes, int n_in,
                              void* d_out, int out_size, void* d_ws, size_t ws_size,
                              hipStream_t stream) {
    const float* Q = (const float*)d_in[0];
    const float* K = (const float*)d_in[1];
    const float* V = (const float*)d_in[2];
    float* Out = (float*)d_out;

    if (ws_size >= WS_NEEDED) {
        short* ws = (short*)d_ws;
        preprocess_kv<<<dim3(NKT, NBH), 256, 0, stream>>>(K, V, ws);
        fa_causal_main<<<dim3(16, NBH), 256, 0, stream>>>(Q, ws, Out);
    } else {
        fa_causal_fallback<<<dim3(16, NBH), 256, 0, stream>>>(Q, K, V, Out);
    }
}